// Round 1
// baseline (234.859 us; speedup 1.0000x reference)
//
#include <hip/hip_runtime.h>
#include <math.h>

#define NB 256       // batch
#define NO 128       // output dim
#define NC 64        // n_caps
#define CD 16        // caps dim
#define PP 1152      // P
#define BO (NB*NO)   // 32768 floats per p-slice
#define BO4 (BO/4)   // 8192 float4 per p-slice

// ---------------- Stage 1: S partials: part[j][b][o] = sum over a p-tile of x[p][b][o]
template<int PT>
__global__ __launch_bounds__(256) void psum_kernel(const float4* __restrict__ x4,
                                                   float4* __restrict__ part4) {
    int bo4 = blockIdx.x * 256 + threadIdx.x;           // 0..8191
    const float4* p = x4 + (size_t)(blockIdx.y * PT) * BO4 + bo4;
    float ax = 0.f, ay = 0.f, az = 0.f, aw = 0.f;
    #pragma unroll
    for (int i = 0; i < PT; ++i) {
        float4 v = p[(size_t)i * BO4];
        ax += v.x; ay += v.y; az += v.z; aw += v.w;
    }
    part4[(size_t)blockIdx.y * BO4 + bo4] = make_float4(ax, ay, az, aw);
}

// ---------------- Stage 2: Wbar[n][o] = sum_c caps_weights[n][c][o]
__global__ __launch_bounds__(256) void wsum_kernel(const float* __restrict__ cw,
                                                   float* __restrict__ Wg) {
    int idx = blockIdx.x * 256 + threadIdx.x;           // 0..8191
    int n = idx >> 7, o = idx & 127;
    float acc = 0.f;
    #pragma unroll
    for (int c = 0; c < CD; ++c) acc += cw[n * CD * NO + c * NO + o];
    Wg[idx] = acc;
}

// ---------------- Stage 3: routing. One block per batch, 128 threads (one per o).
__global__ __launch_bounds__(128) void route_kernel(const float* __restrict__ part,
                                                    const float* __restrict__ Wg,
                                                    float* __restrict__ out,
                                                    int NPart) {
    __shared__ float W_s[NC][NO + 1];   // stride 129: breaks 32-way conflict on W_s[lane][oo]
    __shared__ float S_s[NO];
    __shared__ float routed_s[NO];
    __shared__ float logits_s[NC];
    __shared__ float coeffs_s[NC];
    __shared__ float red[2];

    const int o = threadIdx.x;          // 0..127
    const int b = blockIdx.x;           // 0..255
    const int lane = o & 63, wid = o >> 6;

    // load Wbar into LDS (coalesced over o)
    #pragma unroll
    for (int n = 0; n < NC; ++n) W_s[n][o] = Wg[n * NO + o];

    // finish the p-reduction: S[b][o]
    float s = 0.f;
    for (int j = 0; j < NPart; ++j) s += part[(size_t)j * BO + b * NO + o];
    S_s[o] = s;

    if (o < NC) { logits_s[o] = 0.f; coeffs_s[o] = 1.f / 64.f; }
    __syncthreads();

    // xp[n][o] = W_s[n][o] * s  (implicit, recomputed on the fly)
    for (int it = 0; it < 2; ++it) {            // ITERATIONS-1 routing updates
        // v[o] = sum_n coeffs[n] * xp[n][o]
        float v = 0.f;
        #pragma unroll
        for (int n = 0; n < NC; ++n) v += coeffs_s[n] * W_s[n][o];
        v *= s;
        // squash: norm over o (128 threads = 2 waves)
        float v2 = v * v;
        #pragma unroll
        for (int m = 32; m >= 1; m >>= 1) v2 += __shfl_xor(v2, m, 64);
        if (lane == 0) red[wid] = v2;
        __syncthreads();
        float nv = red[0] + red[1];
        float norm = sqrtf(nv);
        float scale = norm / (1.f + nv);
        routed_s[o] = scale * v;
        __syncthreads();
        // logits[n] += sum_o routed[o] * xp[n][o]; softmax over n (wave 0 only)
        if (o < NC) {
            float acc = 0.f;
            #pragma unroll 8
            for (int oo = 0; oo < NO; ++oo)
                acc += routed_s[oo] * W_s[o][oo] * S_s[oo];
            float lg = logits_s[o] + acc;
            logits_s[o] = lg;
            float mx = lg;
            #pragma unroll
            for (int m = 32; m >= 1; m >>= 1) mx = fmaxf(mx, __shfl_xor(mx, m, 64));
            float e = expf(lg - mx);
            float Z = e;
            #pragma unroll
            for (int m = 32; m >= 1; m >>= 1) Z += __shfl_xor(Z, m, 64);
            coeffs_s[o] = e / Z;
        }
        __syncthreads();
    }

    // final: out[b][o] = squash(sum_n coeffs[n] * xp[n][o])
    float v = 0.f;
    #pragma unroll
    for (int n = 0; n < NC; ++n) v += coeffs_s[n] * W_s[n][o];
    v *= s;
    float v2 = v * v;
    #pragma unroll
    for (int m = 32; m >= 1; m >>= 1) v2 += __shfl_xor(v2, m, 64);
    if (lane == 0) red[wid] = v2;
    __syncthreads();
    float nv = red[0] + red[1];
    float norm = sqrtf(nv);
    float scale = norm / (1.f + nv);
    out[b * NO + o] = scale * v;
}

extern "C" void kernel_launch(void* const* d_in, const int* in_sizes, int n_in,
                              void* d_out, int out_size, void* d_ws, size_t ws_size,
                              hipStream_t stream) {
    const float* x  = (const float*)d_in[0];   // (1152, 256, 128)
    const float* cw = (const float*)d_in[1];   // (64, 16, 128)
    float* out = (float*)d_out;                // (256, 1, 128)

    // pick the largest partial count that fits the workspace
    static const int pts[4] = {16, 32, 64, 128};   // p-tile sizes (PP divisible by each)
    int PT = 128, NP = PP / 128;
    for (int i = 0; i < 4; ++i) {
        int np = PP / pts[i];
        size_t need = (size_t)np * BO * sizeof(float) + (size_t)NC * NO * sizeof(float);
        if (need <= ws_size) { PT = pts[i]; NP = np; break; }
    }

    float* part = (float*)d_ws;
    float* Wg   = part + (size_t)NP * BO;

    dim3 g1(BO4 / 256, PP / PT);
    switch (PT) {
        case 16:  psum_kernel<16> <<<g1, 256, 0, stream>>>((const float4*)x, (float4*)part); break;
        case 32:  psum_kernel<32> <<<g1, 256, 0, stream>>>((const float4*)x, (float4*)part); break;
        case 64:  psum_kernel<64> <<<g1, 256, 0, stream>>>((const float4*)x, (float4*)part); break;
        default:  psum_kernel<128><<<g1, 256, 0, stream>>>((const float4*)x, (float4*)part); break;
    }
    wsum_kernel<<<dim3((NC * NO) / 256), 256, 0, stream>>>(cw, Wg);
    route_kernel<<<dim3(NB), 128, 0, stream>>>(part, Wg, out, NP);
}

// Round 2
// 219.251 us; speedup vs baseline: 1.0712x; 1.0712x over previous
//
#include <hip/hip_runtime.h>
#include <math.h>

#define NB 256       // batch
#define NO 128       // output dim
#define NC 64        // n_caps
#define CD 16        // caps dim
#define PP 1152      // P
#define BO (NB*NO)   // 32768 floats per p-slice
#define BO4 (BO/4)   // 8192 float4 per p-slice

// Stage 1 (fused): blocks y < PP/PT reduce a p-tile of x into partials;
// the extra y == PP/PT slice computes Wbar[n][o] = sum_c cw[n][c][o].
template<int PT>
__global__ __launch_bounds__(256) void psum_kernel(const float4* __restrict__ x4,
                                                   float4* __restrict__ part4,
                                                   const float* __restrict__ cw,
                                                   float* __restrict__ Wg) {
    if ((int)blockIdx.y == PP / PT) {                    // wsum slice (8192 threads)
        int idx = blockIdx.x * 256 + threadIdx.x;        // 0..8191
        int n = idx >> 7, o = idx & 127;
        float acc = 0.f;
        #pragma unroll
        for (int c = 0; c < CD; ++c) acc += cw[n * CD * NO + c * NO + o];
        Wg[idx] = acc;
        return;
    }
    int bo4 = blockIdx.x * 256 + threadIdx.x;            // 0..8191
    const float4* p = x4 + (size_t)(blockIdx.y * PT) * BO4 + bo4;
    float ax = 0.f, ay = 0.f, az = 0.f, aw = 0.f;
    #pragma unroll
    for (int i = 0; i < PT; ++i) {
        float4 v = p[(size_t)i * BO4];
        ax += v.x; ay += v.y; az += v.z; aw += v.w;
    }
    part4[(size_t)blockIdx.y * BO4 + bo4] = make_float4(ax, ay, az, aw);
}

// Stage 2: routing. One block per batch, 256 threads.
// Part reduction: float4 loads, 8 j-chunks x 32 o4-columns, LDS combine.
// Routing phase runs on threads 0..127 (one per o); softmax on wave 0.
template<int NP>
__global__ __launch_bounds__(256) void route_kernel(const float4* __restrict__ part4,
                                                    const float* __restrict__ Wg,
                                                    float* __restrict__ out) {
    __shared__ float  W_s[NC][NO + 1];   // stride 129: conflict-free W_s[lane][oo]
    __shared__ float4 S_red4[8][32];
    __shared__ float  S_s[NO];
    __shared__ float  routed_s[NO];
    __shared__ float  logits_s[NC];
    __shared__ float  coeffs_s[NC];
    __shared__ float  red[2];

    const int t = threadIdx.x;           // 0..255
    const int b = blockIdx.x;            // 0..255
    const int lane = t & 63, wid = t >> 6;

    // Wbar -> LDS (coalesced)
    for (int i = t; i < NC * NO; i += 256) W_s[i >> 7][i & 127] = Wg[i];

    // vectorized partial reduction: thread (jc, o4) sums j = jc, jc+8, ...
    {
        int o4 = t & 31, jc = t >> 5;
        float4 a = make_float4(0.f, 0.f, 0.f, 0.f);
        for (int j = jc; j < NP; j += 8) {
            float4 v = part4[(size_t)j * BO4 + b * 32 + o4];
            a.x += v.x; a.y += v.y; a.z += v.z; a.w += v.w;
        }
        S_red4[jc][o4] = a;
    }
    if (t < NC) { logits_s[t] = 0.f; coeffs_s[t] = 1.f / 64.f; }
    __syncthreads();

    float s = 0.f;
    if (t < 128) {
        const float* sr = (const float*)S_red4;          // flat: jc*128 + o
        #pragma unroll
        for (int jc = 0; jc < 8; ++jc) s += sr[jc * 128 + t];
        S_s[t] = s;
    }
    __syncthreads();

    for (int it = 0; it < 2; ++it) {                     // ITERATIONS-1 updates
        float v = 0.f;
        if (t < 128) {
            #pragma unroll
            for (int n = 0; n < NC; ++n) v += coeffs_s[n] * W_s[n][t];
            v *= s;
            float v2 = v * v;
            #pragma unroll
            for (int m = 32; m >= 1; m >>= 1) v2 += __shfl_xor(v2, m, 64);
            if (lane == 0) red[wid] = v2;
        }
        __syncthreads();
        if (t < 128) {
            float nv = red[0] + red[1];
            float scale = sqrtf(nv) / (1.f + nv);
            routed_s[t] = scale * v;
        }
        __syncthreads();
        if (t < NC) {                                    // wave 0 only
            float acc = 0.f;
            #pragma unroll 8
            for (int oo = 0; oo < NO; ++oo)
                acc += routed_s[oo] * W_s[t][oo] * S_s[oo];
            float lg = logits_s[t] + acc;
            logits_s[t] = lg;
            float mx = lg;
            #pragma unroll
            for (int m = 32; m >= 1; m >>= 1) mx = fmaxf(mx, __shfl_xor(mx, m, 64));
            float e = expf(lg - mx);
            float Z = e;
            #pragma unroll
            for (int m = 32; m >= 1; m >>= 1) Z += __shfl_xor(Z, m, 64);
            coeffs_s[t] = e / Z;
        }
        __syncthreads();
    }

    // final squash + store
    float v = 0.f;
    if (t < 128) {
        #pragma unroll
        for (int n = 0; n < NC; ++n) v += coeffs_s[n] * W_s[n][t];
        v *= s;
        float v2 = v * v;
        #pragma unroll
        for (int m = 32; m >= 1; m >>= 1) v2 += __shfl_xor(v2, m, 64);
        if (lane == 0) red[wid] = v2;
    }
    __syncthreads();
    if (t < 128) {
        float nv = red[0] + red[1];
        float scale = sqrtf(nv) / (1.f + nv);
        out[b * NO + t] = scale * v;
    }
}

extern "C" void kernel_launch(void* const* d_in, const int* in_sizes, int n_in,
                              void* d_out, int out_size, void* d_ws, size_t ws_size,
                              hipStream_t stream) {
    const float* x  = (const float*)d_in[0];   // (1152, 256, 128)
    const float* cw = (const float*)d_in[1];   // (64, 16, 128)
    float* out = (float*)d_out;                // (256, 1, 128)
    float* part = (float*)d_ws;

    const size_t need48 = (size_t)(PP / 48) * BO * sizeof(float) + (size_t)NC * NO * sizeof(float);
    if (ws_size >= need48) {
        // PT=48 -> NP=24 partials (3.1 MB), grid 768+32 blocks
        float* Wg = part + (size_t)(PP / 48) * BO;
        psum_kernel<48><<<dim3(32, PP / 48 + 1), 256, 0, stream>>>(
            (const float4*)x, (float4*)part, cw, Wg);
        route_kernel<24><<<dim3(NB), 256, 0, stream>>>((const float4*)part, Wg, out);
    } else {
        // fallback: PT=128 -> NP=9 partials (1.2 MB)
        float* Wg = part + (size_t)(PP / 128) * BO;
        psum_kernel<128><<<dim3(32, PP / 128 + 1), 256, 0, stream>>>(
            (const float4*)x, (float4*)part, cw, Wg);
        route_kernel<9><<<dim3(NB), 256, 0, stream>>>((const float4*)part, Wg, out);
    }
}

// Round 3
// 216.918 us; speedup vs baseline: 1.0827x; 1.0108x over previous
//
#include <hip/hip_runtime.h>
#include <math.h>

#define NB 256       // batch
#define NO 128       // output dim
#define NC 64        // n_caps
#define CD 16        // caps dim
#define PP 1152      // P
#define BO4 8192     // float4 per p-slice (256*128/4)

// One block per batch element. 512 threads = 8 waves.
// Phase A: reduce x[:,b,:] over p (151 MB total across grid, coalesced).
// Phase B: Wbar[n][o] = sum_c cw[n][c][o] into LDS (cw L2-resident).
// Phase C/D: dynamic routing entirely in LDS/registers.
__global__ __launch_bounds__(512) void capsule_kernel(const float4* __restrict__ x4,
                                                      const float4* __restrict__ cw4,
                                                      float* __restrict__ out) {
    __shared__ float  W_s[NC][NO + 1];   // stride 129: W_s[lane][oo] conflict-free
    __shared__ float4 S_red4[16][32];
    __shared__ float  S_s[NO];
    __shared__ float  routed_s[NO];
    __shared__ float  logits_s[NC];
    __shared__ float  coeffs_s[NC];
    __shared__ float  red[2];

    const int t = threadIdx.x;           // 0..511
    const int b = blockIdx.x;            // 0..255
    const int o4 = t & 31, pc = t >> 5;  // column, p-chunk (0..15)
    const int lane = t & 63, wid = t >> 6;

    // ---- Phase A: p-reduction. 72 strided rows per thread, unroll 8.
    {
        const float4* p = x4 + (size_t)pc * BO4 + b * 32 + o4;
        float ax = 0.f, ay = 0.f, az = 0.f, aw = 0.f;
        #pragma unroll 8
        for (int j = 0; j < PP / 16; ++j) {
            float4 v = p[(size_t)j * 16 * BO4];
            ax += v.x; ay += v.y; az += v.z; aw += v.w;
        }
        S_red4[pc][o4] = make_float4(ax, ay, az, aw);
    }

    // ---- Phase B: Wbar into LDS. 2048 (n,o4) pairs, 4 per thread.
    #pragma unroll
    for (int k = 0; k < 4; ++k) {
        int idx = t + k * 512;           // 0..2047
        int n = idx >> 5, oq = idx & 31;
        float4 a = make_float4(0.f, 0.f, 0.f, 0.f);
        #pragma unroll
        for (int c = 0; c < CD; ++c) {
            float4 v = cw4[n * (CD * 32) + c * 32 + oq];
            a.x += v.x; a.y += v.y; a.z += v.z; a.w += v.w;
        }
        W_s[n][4 * oq + 0] = a.x; W_s[n][4 * oq + 1] = a.y;
        W_s[n][4 * oq + 2] = a.z; W_s[n][4 * oq + 3] = a.w;
    }

    if (t < NC) { logits_s[t] = 0.f; coeffs_s[t] = 1.f / 64.f; }
    __syncthreads();

    // ---- Phase C: combine the 16 p-chunk partials -> S[b][o]
    float s = 0.f;
    if (t < NO) {
        const float* sr = (const float*)S_red4;   // flat: pc*128 + o
        #pragma unroll
        for (int j = 0; j < 16; ++j) s += sr[j * 128 + t];
        S_s[t] = s;
    }
    __syncthreads();

    // ---- Phase D: routing (xp[n][o] = W_s[n][o] * s, recomputed on the fly)
    for (int it = 0; it < 2; ++it) {              // ITERATIONS-1 updates
        float v = 0.f;
        if (t < NO) {
            #pragma unroll
            for (int n = 0; n < NC; ++n) v += coeffs_s[n] * W_s[n][t];
            v *= s;
            float v2 = v * v;
            #pragma unroll
            for (int m = 32; m >= 1; m >>= 1) v2 += __shfl_xor(v2, m, 64);
            if (lane == 0) red[wid] = v2;
        }
        __syncthreads();
        if (t < NO) {
            float nv = red[0] + red[1];
            float scale = sqrtf(nv) / (1.f + nv);
            routed_s[t] = scale * v;
        }
        __syncthreads();
        if (t < NC) {                             // softmax on wave 0
            float acc = 0.f;
            #pragma unroll 8
            for (int oo = 0; oo < NO; ++oo)
                acc += routed_s[oo] * W_s[t][oo] * S_s[oo];
            float lg = logits_s[t] + acc;
            logits_s[t] = lg;
            float mx = lg;
            #pragma unroll
            for (int m = 32; m >= 1; m >>= 1) mx = fmaxf(mx, __shfl_xor(mx, m, 64));
            float e = expf(lg - mx);
            float Z = e;
            #pragma unroll
            for (int m = 32; m >= 1; m >>= 1) Z += __shfl_xor(Z, m, 64);
            coeffs_s[t] = e / Z;
        }
        __syncthreads();
    }

    // ---- final squash + store
    float v = 0.f;
    if (t < NO) {
        #pragma unroll
        for (int n = 0; n < NC; ++n) v += coeffs_s[n] * W_s[n][t];
        v *= s;
        float v2 = v * v;
        #pragma unroll
        for (int m = 32; m >= 1; m >>= 1) v2 += __shfl_xor(v2, m, 64);
        if (lane == 0) red[wid] = v2;
    }
    __syncthreads();
    if (t < NO) {
        float nv = red[0] + red[1];
        float scale = sqrtf(nv) / (1.f + nv);
        out[b * NO + t] = scale * v;
    }
}

extern "C" void kernel_launch(void* const* d_in, const int* in_sizes, int n_in,
                              void* d_out, int out_size, void* d_ws, size_t ws_size,
                              hipStream_t stream) {
    const float* x  = (const float*)d_in[0];   // (1152, 256, 128)
    const float* cw = (const float*)d_in[1];   // (64, 16, 128)
    float* out = (float*)d_out;                // (256, 1, 128)
    capsule_kernel<<<dim3(NB), 512, 0, stream>>>((const float4*)x, (const float4*)cw, out);
}

// Round 5
// 205.469 us; speedup vs baseline: 1.1430x; 1.0557x over previous
//
#include <hip/hip_runtime.h>
#include <math.h>

#define NB 256       // batch
#define NO 128       // output dim
#define NC 64        // n_caps
#define CD 16        // caps dim
#define PP 1152      // P
#define BO4 8192     // float4 per p-slice (256*128/4)

typedef float nt_float4 __attribute__((ext_vector_type(4)));  // builtin-compatible

// One block per batch element. 1024 threads = 16 waves (16 waves/CU at grid=256).
// Phase A: reduce x[:,b,:] over p (151 MB total across grid, coalesced, nontemporal).
// Phase B: Wbar[n][o] = sum_c cw[n][c][o] into LDS (cw stays L2-resident).
// Phase C/D: dynamic routing entirely in LDS/registers.
__global__ __launch_bounds__(1024) void capsule_kernel(const nt_float4* __restrict__ x4,
                                                       const float4* __restrict__ cw4,
                                                       float* __restrict__ out) {
    __shared__ float  W_s[NC][NO + 1];   // stride 129: W_s[lane][oo] conflict-free
    __shared__ float  S_red[32][NO];     // 16 KB, [pc][o]
    __shared__ float  S_s[NO];
    __shared__ float  routed_s[NO];
    __shared__ float  logits_s[NC];
    __shared__ float  coeffs_s[NC];
    __shared__ float  red[2];

    const int t = threadIdx.x;           // 0..1023
    const int b = blockIdx.x;            // 0..255
    const int o4 = t & 31, pc = t >> 5;  // column, p-chunk (0..31)
    const int lane = t & 63, wid = t >> 6;

    // ---- Phase A: p-reduction. 36 strided rows per thread, nontemporal.
    {
        const nt_float4* p = x4 + (size_t)pc * BO4 + b * 32 + o4;
        nt_float4 a = (nt_float4)(0.f);
        #pragma unroll 12
        for (int j = 0; j < PP / 32; ++j) {
            nt_float4 v = __builtin_nontemporal_load(p + (size_t)j * 32 * BO4);
            a += v;
        }
        S_red[pc][4 * o4 + 0] = a.x; S_red[pc][4 * o4 + 1] = a.y;
        S_red[pc][4 * o4 + 2] = a.z; S_red[pc][4 * o4 + 3] = a.w;
    }

    // ---- Phase B: Wbar into LDS. 2048 (n,o4) pairs, 2 per thread.
    #pragma unroll
    for (int k = 0; k < 2; ++k) {
        int idx = t + k * 1024;          // 0..2047
        int n = idx >> 5, oq = idx & 31;
        float4 a = make_float4(0.f, 0.f, 0.f, 0.f);
        #pragma unroll
        for (int c = 0; c < CD; ++c) {
            float4 v = cw4[n * (CD * 32) + c * 32 + oq];
            a.x += v.x; a.y += v.y; a.z += v.z; a.w += v.w;
        }
        W_s[n][4 * oq + 0] = a.x; W_s[n][4 * oq + 1] = a.y;
        W_s[n][4 * oq + 2] = a.z; W_s[n][4 * oq + 3] = a.w;
    }

    if (t < NC) { logits_s[t] = 0.f; coeffs_s[t] = 1.f / 64.f; }
    __syncthreads();

    // ---- Phase C: combine the 32 p-chunk partials -> S[b][o]
    float s = 0.f;
    if (t < NO) {
        #pragma unroll
        for (int j = 0; j < 32; ++j) s += S_red[j][t];
        S_s[t] = s;
    }
    __syncthreads();

    // ---- Phase D: routing (xp[n][o] = W_s[n][o] * s, recomputed on the fly)
    for (int it = 0; it < 2; ++it) {              // ITERATIONS-1 updates
        float v = 0.f;
        if (t < NO) {
            #pragma unroll
            for (int n = 0; n < NC; ++n) v += coeffs_s[n] * W_s[n][t];
            v *= s;
            float v2 = v * v;
            #pragma unroll
            for (int m = 32; m >= 1; m >>= 1) v2 += __shfl_xor(v2, m, 64);
            if (lane == 0) red[wid] = v2;
        }
        __syncthreads();
        if (t < NO) {
            float nv = red[0] + red[1];
            float scale = sqrtf(nv) / (1.f + nv);
            routed_s[t] = scale * v;
        }
        __syncthreads();
        if (t < NC) {                             // softmax on wave 0
            float acc = 0.f;
            #pragma unroll 8
            for (int oo = 0; oo < NO; ++oo)
                acc += routed_s[oo] * W_s[t][oo] * S_s[oo];
            float lg = logits_s[t] + acc;
            logits_s[t] = lg;
            float mx = lg;
            #pragma unroll
            for (int m = 32; m >= 1; m >>= 1) mx = fmaxf(mx, __shfl_xor(mx, m, 64));
            float e = expf(lg - mx);
            float Z = e;
            #pragma unroll
            for (int m = 32; m >= 1; m >>= 1) Z += __shfl_xor(Z, m, 64);
            coeffs_s[t] = e / Z;
        }
        __syncthreads();
    }

    // ---- final squash + store
    float v = 0.f;
    if (t < NO) {
        #pragma unroll
        for (int n = 0; n < NC; ++n) v += coeffs_s[n] * W_s[n][t];
        v *= s;
        float v2 = v * v;
        #pragma unroll
        for (int m = 32; m >= 1; m >>= 1) v2 += __shfl_xor(v2, m, 64);
        if (lane == 0) red[wid] = v2;
    }
    __syncthreads();
    if (t < NO) {
        float nv = red[0] + red[1];
        float scale = sqrtf(nv) / (1.f + nv);
        out[b * NO + t] = scale * v;
    }
}

extern "C" void kernel_launch(void* const* d_in, const int* in_sizes, int n_in,
                              void* d_out, int out_size, void* d_ws, size_t ws_size,
                              hipStream_t stream) {
    const float* x  = (const float*)d_in[0];   // (1152, 256, 128)
    const float* cw = (const float*)d_in[1];   // (64, 16, 128)
    float* out = (float*)d_out;                // (256, 1, 128)
    capsule_kernel<<<dim3(NB), 1024, 0, stream>>>((const nt_float4*)x, (const float4*)cw, out);
}